// Round 1
// 216.525 us; speedup vs baseline: 1.3458x; 1.3458x over previous
//
#include <hip/hip_runtime.h>
#include <hip/hip_bf16.h>

#define EPS 1e-8f
#define B_  16
#define CIN 256
#define COUT 256
#define HW 64

typedef __bf16 bf16x8 __attribute__((ext_vector_type(8)));
typedef float  f32x4  __attribute__((ext_vector_type(4)));

__device__ __forceinline__ void async16(void* lds, const void* g) {
    __builtin_amdgcn_global_load_lds(
        (const __attribute__((address_space(1))) unsigned int*)g,
        (__attribute__((address_space(3))) unsigned int*)lds,
        16, 0, 0);
}

// ---------------- fused stats: blocks 0..255 = per-co wsq/wn_scale; block 256 = ssum ----------------
__global__ __launch_bounds__(256) void stats_kernel(const float* __restrict__ w,
                                                    const float* __restrict__ s,
                                                    float* __restrict__ wsq,
                                                    float* __restrict__ wn_scale,
                                                    float* __restrict__ ssum_out) {
    __shared__ float smem[4];
    const int t = threadIdx.x;
    const int lane = t & 63, wid = t >> 6;
    if (blockIdx.x == 256) {
        float v = 0.f;
        for (int i = t; i < B_ * CIN; i += 256) { float sv = s[i]; v += sv * sv; }
        for (int off = 32; off > 0; off >>= 1) v += __shfl_down(v, off, 64);
        if (lane == 0) smem[wid] = v;
        __syncthreads();
        if (t == 0) ssum_out[0] = smem[0] + smem[1] + smem[2] + smem[3];
        return;
    }
    const int co = blockIdx.x;
    const float* wp = w + ((size_t)co * CIN + t) * 9;
    float q = 0.f;
#pragma unroll
    for (int tp = 0; tp < 9; ++tp) { float wv = wp[tp]; q += wv * wv; }
    wsq[co * CIN + t] = q;
    float v = q;
    for (int off = 32; off > 0; off >>= 1) v += __shfl_down(v, off, 64);
    if (lane == 0) smem[wid] = v;
    __syncthreads();
    if (t == 0) wn_scale[co] = rsqrtf((smem[0] + smem[1] + smem[2] + smem[3]) / 2304.f);
}

// ---------------- fused coef + modulated-weight materialization ----------------
// NEW wfull layout: [b][tap][cc=ci>>5][co][ci&31]  (ci-chunk-major so conv A-frag
// loads are one contiguous 1 KB per 64-lane load instead of 16x 64B segments).
__global__ __launch_bounds__(256) void wmod_kernel(const float* __restrict__ w,
                                                   const float* __restrict__ s,
                                                   const float* __restrict__ wsq,
                                                   const float* __restrict__ wn_scale,
                                                   const float* __restrict__ ssum,
                                                   __bf16* __restrict__ wfull) {
    __shared__ float smem[4];
    __shared__ float coef_s;
    const int co = blockIdx.x;
    const int b  = blockIdx.y;
    const int ci = threadIdx.x;
    const int lane = ci & 63, wid = ci >> 6;
    const float sv = s[b * CIN + ci];
    float v = sv * sv * wsq[co * CIN + ci];
    for (int off = 32; off > 0; off >>= 1) v += __shfl_down(v, off, 64);
    if (lane == 0) smem[wid] = v;
    __syncthreads();
    if (ci == 0) {
        float S = smem[0] + smem[1] + smem[2] + smem[3];
        float sn2 = (float)(B_ * CIN) / ssum[0];
        float wn = wn_scale[co];
        coef_s = wn * sqrtf(sn2) * rsqrtf(wn * wn * sn2 * S + EPS);
    }
    __syncthreads();
    const float sc = sv * coef_s;
    const float* wp = w + ((size_t)co * CIN + ci) * 9;
    float wv[9];
#pragma unroll
    for (int tp = 0; tp < 9; ++tp) wv[tp] = wp[tp];
    const size_t obase = ((size_t)b * 9) * 65536 + (size_t)(ci >> 5) * 8192
                       + (size_t)co * 32 + (ci & 31);
#pragma unroll
    for (int tap = 0; tap < 9; ++tap)
        wfull[obase + (size_t)tap * 65536] = (__bf16)(wv[tap] * sc);
}

// ---------------- x fp32 NCHW -> bf16 [b][row][col 0..65][ci], via LDS transpose ----------------
// TP=258 elements = 129 dwords: write lane row-stride 4*129 dw == 4 mod 32 -> 2-way (free).
#define TP 258
__global__ __launch_bounds__(256) void xbf2_kernel(const float* __restrict__ x,
                                                   __bf16* __restrict__ xbf) {
    __shared__ __bf16 xs[64 * TP];
    const int row = blockIdx.x;
    const int b   = blockIdx.y;
    const int t   = threadIdx.x;
    const float* xbase = x + ((size_t)b * CIN * HW + row) * HW;
#pragma unroll
    for (int k = 0; k < 16; ++k) {
        int idx = k * 256 + t;
        int ci = idx >> 4;
        int c4 = (idx & 15) * 4;
        float4 v = *(const float4*)(xbase + (size_t)ci * (HW * HW) + c4);
        xs[(c4 + 0) * TP + ci] = (__bf16)v.x;
        xs[(c4 + 1) * TP + ci] = (__bf16)v.y;
        xs[(c4 + 2) * TP + ci] = (__bf16)v.z;
        xs[(c4 + 3) * TP + ci] = (__bf16)v.w;
    }
    __syncthreads();
    uint* orow = (uint*)(xbf + (((size_t)b * HW + row) * 66) * CIN);
#pragma unroll
    for (int k = 0; k < 17; ++k) {
        int idx = k * 256 + t;
        if (idx < 66 * 64) {
            int col = idx >> 6;          // 0..65
            int ci4 = (idx & 63) * 4;
            uint u0 = 0, u1 = 0;
            if (col != 0 && col != 65) {
                u0 = *(const uint*)&xs[(col - 1) * TP + ci4];
                u1 = *(const uint*)&xs[(col - 1) * TP + ci4 + 2];
            }
            orow[(col * CIN + ci4) >> 1] = u0;
            orow[((col * CIN + ci4) >> 1) + 1] = u1;
        }
    }
}

// ---------------- MFMA implicit-GEMM conv, v4 ----------------
// grid 1024 (XCD-affine: b = bid%8 + 8*(bid>=512), row = (bid>>3)&63), block 256 = 4 waves.
// wave wy = co quarter (64 co); each wave computes one output row (64 px) via 4x4 MFMA tiles.
// v4: wfull re-blocked [b][tap][cc][co][ci32] -> each A-frag load is one contiguous
// 1 KB (8 full 128B lines) instead of 16 scattered 64B segments; + setprio around MFMAs.
// Software-pipelined A-frag loads (tap+1 prefetch) + double-buffered async x staging.
// LDS x tile (per buf): 800 slots of 16B: slot = qq*200 + irow*66 + col (qq=ci octet, irow 0..2).
__global__ __launch_bounds__(256, 3) void conv_mfma3(const __bf16* __restrict__ xbf,
                                                     const __bf16* __restrict__ zrow,
                                                     const __bf16* __restrict__ wfull,
                                                     float* __restrict__ out) {
    __shared__ __attribute__((aligned(16))) __bf16 xs[2][800 * 8];   // 2 x 12800 B

    const int bid = blockIdx.x;
    const int b    = (bid & 7) + ((bid >= 512) ? 8 : 0);
    const int row0 = (bid >> 3) & 63;
    const int t = threadIdx.x;
    const int wy = t >> 6, lane = t & 63;
    const int m16 = lane & 15, q = lane >> 4;

    // staging sources: up to 4 async16 per thread over 800 slots (+224 dead lanes)
    const __bf16* gsrc[4];
    unsigned ldsoff[4];
    bool val[4];
#pragma unroll
    for (int i = 0; i < 4; ++i) {
        int slot = i * 256 + t;
        val[i] = slot < 800;
        int qq  = slot / 200;
        int rem = slot - qq * 200;
        int irow = rem / 66;
        int col  = rem - irow * 66;
        const __bf16* g;
        if (!val[i] || rem >= 198) {
            g = zrow;
        } else {
            int gr = row0 - 1 + irow;
            if ((unsigned)gr < 64u)
                g = xbf + (((size_t)b * HW + gr) * 66 + col) * CIN + qq * 8;
            else
                g = zrow + col * CIN + qq * 8;
        }
        gsrc[i] = g;
        ldsoff[i] = (unsigned)slot * 16;
    }

    // prologue: stage chunk 0 into buf 0
#pragma unroll
    for (int i = 0; i < 4; ++i)
        if (val[i]) async16((char*)xs[0] + ldsoff[i], gsrc[i]);

    f32x4 acc[4][4] = {};
    // A base: wfull[b][tap][cc][co = wy*64 + i*16 + m16][ci32 = q*8 .. +7]
    // lane offset = m16*64B + q*16B -> 64 lanes tile one contiguous 1 KB per frag.
    const __bf16* abase = wfull + (size_t)b * 589824
                        + (size_t)(wy * 64 + m16) * 32 + q * 8;

    for (int cc = 0; cc < 8; ++cc) {
        __syncthreads();                       // drains chunk-cc staging (issued one chunk ago)
        if (cc < 7) {
#pragma unroll
            for (int i = 0; i < 4; ++i)
                if (val[i]) async16((char*)xs[(cc + 1) & 1] + ldsoff[i], gsrc[i] + cc * 32 + 32);
        }
        const __bf16* wb = abase + (size_t)cc * 8192;
        const __bf16* xcur = xs[cc & 1];

        bf16x8 afc[4];
#pragma unroll
        for (int i = 0; i < 4; ++i)
            afc[i] = *(const bf16x8*)(wb + i * 512);

#pragma unroll
        for (int tap = 0; tap < 9; ++tap) {
            bf16x8 afn[4];
            if (tap < 8) {
#pragma unroll
                for (int i = 0; i < 4; ++i)
                    afn[i] = *(const bf16x8*)(wb + (size_t)(tap + 1) * 65536 + i * 512);
            }
            const int dr = tap / 3, dc = tap % 3;
            bf16x8 bfr[4];
            const int rb = (q * 200 + dr * 66 + (m16 + dc)) * 8;
#pragma unroll
            for (int j = 0; j < 4; ++j)
                bfr[j] = *(const bf16x8*)&xcur[rb + j * 16 * 8];
            __builtin_amdgcn_s_setprio(1);
#pragma unroll
            for (int i = 0; i < 4; ++i)
#pragma unroll
                for (int j = 0; j < 4; ++j)
                    acc[i][j] = __builtin_amdgcn_mfma_f32_16x16x32_bf16(afc[i], bfr[j], acc[i][j], 0, 0, 0);
            __builtin_amdgcn_s_setprio(0);
            if (tap < 8) {
#pragma unroll
                for (int i = 0; i < 4; ++i) afc[i] = afn[i];
            }
        }
    }

    // epilogue: D col = lane&15 (pixel), row = q*4+reg (co)
#pragma unroll
    for (int i = 0; i < 4; ++i) {
        const int cobase = wy * 64 + i * 16 + q * 4;
#pragma unroll
        for (int reg = 0; reg < 4; ++reg) {
            float* op = out + ((size_t)b * COUT + (cobase + reg)) * (HW * HW) + row0 * HW;
#pragma unroll
            for (int j = 0; j < 4; ++j)
                op[j * 16 + m16] = acc[i][j][reg];
        }
    }
}

extern "C" void kernel_launch(void* const* d_in, const int* in_sizes, int n_in,
                              void* d_out, int out_size, void* d_ws, size_t ws_size,
                              hipStream_t stream) {
    const float* x = (const float*)d_in[0];
    const float* s = (const float*)d_in[1];
    const float* w = (const float*)d_in[2];
    float* out = (float*)d_out;

    float* ws = (float*)d_ws;
    float*  ssum     = ws;
    float*  wn_scale = ws + 16;
    float*  wsq      = ws + 512;
    __bf16* wfull    = (__bf16*)(ws + 70656);            // 18,874,368 B
    __bf16* zrow     = (__bf16*)(ws + 4789248);          // 33,792 B
    __bf16* xbf      = (__bf16*)(ws + 4797696);          // 34,603,008 B

    hipMemsetAsync(zrow, 0, 33792, stream);
    stats_kernel<<<257, 256, 0, stream>>>(w, s, wsq, wn_scale, ssum);
    wmod_kernel<<<dim3(COUT, B_), 256, 0, stream>>>(w, s, wsq, wn_scale, ssum, wfull);
    xbf2_kernel<<<dim3(64, B_), 256, 0, stream>>>(x, xbf);
    conv_mfma3<<<1024, 256, 0, stream>>>(xbf, zrow, wfull, out);
}